// Round 2
// baseline (1680.361 us; speedup 1.0000x reference)
//
#include <hip/hip_runtime.h>
#include <hip/hip_bf16.h>
#include <stdint.h>

// Problem constants
#define B_ 128
#define T_ 40
#define E_ 512
#define H_ 512
#define G_ 2048   // 4*H gates
#define V_ 10000
#define F_ 2048   // fc_feat

typedef __attribute__((ext_vector_type(8))) short short8;
typedef __attribute__((ext_vector_type(4))) float f32x4;

__device__ __forceinline__ float bf2f(short s) {
    unsigned u = ((unsigned)(unsigned short)s) << 16;
    float f;
    __builtin_memcpy(&f, &u, 4);
    return f;
}
__device__ __forceinline__ short f2bf(float f) {
    unsigned u;
    __builtin_memcpy(&u, &f, 4);
    u = (u + 0x7fffu + ((u >> 16) & 1u)) >> 16;
    return (short)u;
}
__device__ __forceinline__ float sigf(float x) { return 1.f / (1.f + __expf(-x)); }
__device__ __forceinline__ float tanh_fast(float x) { return 2.f / (1.f + __expf(-2.f * x)) - 1.f; }

// ---------------------------------------------------------------------------
// f32 -> bf16 convert (grid-stride)
__global__ __launch_bounds__(256) void convert_k(const float* __restrict__ src,
                                                 short* __restrict__ dst, int n) {
    int stride = gridDim.x * blockDim.x;
    for (int i = blockIdx.x * blockDim.x + threadIdx.x; i < n; i += stride)
        dst[i] = f2bf(src[i]);
}

// combined biases: bias = bih + bhh, for both cells
__global__ __launch_bounds__(256) void bias2_k(const float* __restrict__ ab, const float* __restrict__ ah,
                                               float* __restrict__ oa,
                                               const float* __restrict__ fb, const float* __restrict__ fh,
                                               float* __restrict__ of) {
    int t = blockIdx.x * 256 + threadIdx.x;
    if (t < G_) oa[t] = ab[t] + ah[t];
    else if (t < 2 * G_) { int u = t - G_; of[u] = fb[u] + fh[u]; }
}

// ---------------------------------------------------------------------------
// Gather word embeddings into bf16 GEMM input rows.
// XaIn row (b,i>=1) = embed[word_idx[b, father_idx[b,i]]]
// XfIn row (b,i)    = 0 if i==0 or (i-1)%3==0 else embed[word_idx[b,i-1]]
__global__ __launch_bounds__(256) void gather_k(const int* __restrict__ word_idx,
                                                const int* __restrict__ father_idx,
                                                const float* __restrict__ embed,
                                                short* __restrict__ XaIn,
                                                short* __restrict__ XfIn) {
    int rr = blockIdx.x;            // rr = b*40 + i
    int i = rr % T_;
    int b = rr / T_;
    if (i >= 1) {
        int fa = father_idx[rr];
        int wa = word_idx[b * T_ + fa];
        const float* src = embed + (size_t)wa * E_;
        for (int t = threadIdx.x; t < E_; t += 256)
            XaIn[(size_t)rr * E_ + t] = f2bf(src[t]);
    }
    bool zf = (i == 0) || (((i - 1) % 3) == 0);
    if (zf) {
        for (int t = threadIdx.x; t < E_; t += 256) XfIn[(size_t)rr * E_ + t] = 0;
    } else {
        int wp = word_idx[rr - 1];  // word_idx[b][i-1]
        const float* src = embed + (size_t)wp * E_;
        for (int t = threadIdx.x; t < E_; t += 256)
            XfIn[(size_t)rr * E_ + t] = f2bf(src[t]);
    }
}

// ---------------------------------------------------------------------------
// Generic MFMA GEMM: C[M,N] = A[M,K](bf16) * B[N,K]^T(bf16) + bias[N]
// block = 256 threads = 4 waves (2x2), block tile 128x128, wave tile 64x64.
// M % 128 == 0 (for grid.y) or M <= 128; N % 16 == 0; K % 32 == 0.
// mfma_f32_16x16x32_bf16 layout: A lane: row=l&15, k=(l>>4)*8+e;
// B lane: col=l&15, k=(l>>4)*8+e; C lane: col=l&15, row=(l>>4)*4+j.
template <int OUT_BF16, int DO_TANH>
__global__ __launch_bounds__(256) void gemm_bt(const short* __restrict__ A, int lda,
                                               const short* __restrict__ B,
                                               const float* __restrict__ bias,
                                               void* __restrict__ C, int ldc,
                                               int M, int N, int K) {
    int wave = threadIdx.x >> 6, lane = threadIdx.x & 63;
    int row0 = blockIdx.y * 128 + (wave >> 1) * 64;
    int col0 = blockIdx.x * 128 + (wave & 1) * 64;
    int r = lane & 15, kg = lane >> 4;
    short8 bz = {0, 0, 0, 0, 0, 0, 0, 0};
    bool cv[4];
    const short *Ab[4], *Bb[4];
#pragma unroll
    for (int t = 0; t < 4; t++) {
        cv[t] = (col0 + t * 16) < N;
        Ab[t] = A + (size_t)(row0 + t * 16 + r) * lda + kg * 8;
        Bb[t] = B + (size_t)(cv[t] ? (col0 + t * 16 + r) : 0) * K + kg * 8;
    }
    f32x4 acc[4][4] = {};
    for (int k0 = 0; k0 < K; k0 += 32) {
        short8 af[4], bf[4];
#pragma unroll
        for (int t = 0; t < 4; t++) af[t] = *(const short8*)(Ab[t] + k0);
#pragma unroll
        for (int t = 0; t < 4; t++) bf[t] = cv[t] ? *(const short8*)(Bb[t] + k0) : bz;
#pragma unroll
        for (int mt = 0; mt < 4; mt++)
#pragma unroll
            for (int nt = 0; nt < 4; nt++)
                acc[mt][nt] = __builtin_amdgcn_mfma_f32_16x16x32_bf16(af[mt], bf[nt], acc[mt][nt], 0, 0, 0);
    }
#pragma unroll
    for (int nt = 0; nt < 4; nt++) {
        if (!cv[nt]) continue;
        int col = col0 + nt * 16 + r;
        float bs = bias ? bias[col] : 0.f;
#pragma unroll
        for (int mt = 0; mt < 4; mt++) {
#pragma unroll
            for (int j = 0; j < 4; j++) {
                int row = row0 + mt * 16 + kg * 4 + j;
                float v = acc[mt][nt][j] + bs;
                if (DO_TANH) v = tanh_fast(v);
                if (OUT_BF16) ((short*)C)[(size_t)row * ldc + col] = f2bf(v);
                else          ((float*)C)[(size_t)row * ldc + col] = v;
            }
        }
    }
}

// ---------------------------------------------------------------------------
// Step 0 elementwise: gates have no h-contribution (h=c=0).
__global__ __launch_bounds__(256) void step0_k(const short* __restrict__ XaP,
                                               const short* __restrict__ XfP,
                                               short* __restrict__ H_all,
                                               float* __restrict__ cS,
                                               float* __restrict__ bcS) {
    int t = blockIdx.x * 256 + threadIdx.x;
    if (t >= B_ * H_) return;
    int b = t >> 9, n = t & (H_ - 1);
    size_t xbase = ((size_t)(b * T_)) * G_ + n;
    {   // ancestor cell
        float gi = bf2f(XaP[xbase]);
        float gg = bf2f(XaP[xbase + 2 * H_]);
        float go = bf2f(XaP[xbase + 3 * H_]);
        float c2 = sigf(gi) * tanh_fast(gg);          // c_prev = 0
        float h2 = sigf(go) * tanh_fast(c2);
        cS[((size_t)(b * T_)) * H_ + n] = c2;
        H_all[(((size_t)(b * T_)) * 2 + 0) * H_ + n] = f2bf(h2);
    }
    {   // fraternal cell (gates = bias_f)
        float gi = bf2f(XfP[xbase]);
        float gg = bf2f(XfP[xbase + 2 * H_]);
        float go = bf2f(XfP[xbase + 3 * H_]);
        float c2 = sigf(gi) * tanh_fast(gg);
        float h2 = sigf(go) * tanh_fast(c2);
        bcS[((size_t)(b * T_)) * H_ + n] = c2;
        H_all[(((size_t)(b * T_)) * 2 + 1) * H_ + n] = f2bf(h2);
    }
}

// ---------------------------------------------------------------------------
// Recurrent step i (i>=1): fused h-side GEMM (both cells) + LSTM elementwise.
// grid = 64 blocks: bit5 = cell, bit4 = row half (64 rows), bits0-3 = unit
// group (32 hidden units). Each wave computes one gate chunk; gate values are
// exchanged through LDS for the elementwise phase.
__global__ __launch_bounds__(256) void step_k(const short* __restrict__ XaP,
                                              const short* __restrict__ XfP,
                                              const short* __restrict__ a_whh_h,
                                              const short* __restrict__ f_whh_h,
                                              short* __restrict__ H_all,
                                              float* __restrict__ cS,
                                              float* __restrict__ bcS,
                                              const int* __restrict__ father_idx,
                                              int i, int reset) {
    int blk = blockIdx.x;
    int cell = blk >> 5;
    int rh = (blk >> 4) & 1;
    int ug = blk & 15;
    int row0 = rh * 64;
    int n0 = ug * 32;
    int wave = threadIdx.x >> 6;   // gate index
    int lane = threadIdx.x & 63;
    __shared__ float lds_g[4][64][33];
    int skip = (cell == 1 && reset);
    if (!skip) {
        int r = lane & 15, kg = lane >> 4;
        const short* Ab[4];
#pragma unroll
        for (int mt = 0; mt < 4; mt++) {
            int b = row0 + mt * 16 + r;
            int si = (cell == 0) ? father_idx[b * T_ + i] : (i - 1);
            Ab[mt] = H_all + (((size_t)(b * T_ + si)) * 2 + cell) * H_ + kg * 8;
        }
        const short* Wh = cell ? f_whh_h : a_whh_h;
        const short* Bb[2];
#pragma unroll
        for (int nt = 0; nt < 2; nt++)
            Bb[nt] = Wh + (size_t)(wave * H_ + n0 + nt * 16 + r) * H_ + kg * 8;
        f32x4 acc[4][2] = {};
        for (int k0 = 0; k0 < H_; k0 += 32) {
            short8 af[4], bfr[2];
#pragma unroll
            for (int mt = 0; mt < 4; mt++) af[mt] = *(const short8*)(Ab[mt] + k0);
#pragma unroll
            for (int nt = 0; nt < 2; nt++) bfr[nt] = *(const short8*)(Bb[nt] + k0);
#pragma unroll
            for (int mt = 0; mt < 4; mt++)
#pragma unroll
                for (int nt = 0; nt < 2; nt++)
                    acc[mt][nt] = __builtin_amdgcn_mfma_f32_16x16x32_bf16(af[mt], bfr[nt], acc[mt][nt], 0, 0, 0);
        }
#pragma unroll
        for (int mt = 0; mt < 4; mt++)
#pragma unroll
            for (int nt = 0; nt < 2; nt++)
#pragma unroll
                for (int j = 0; j < 4; j++)
                    lds_g[wave][mt * 16 + kg * 4 + j][nt * 16 + r] = acc[mt][nt][j];
    }
    __syncthreads();
    const short* XP = cell ? XfP : XaP;
    for (int t = threadIdx.x; t < 64 * 32; t += 256) {
        int br = t >> 5;
        int b = row0 + br;
        int nn = t & 31;
        int n = n0 + nn;
        size_t xbase = ((size_t)(b * T_ + i)) * G_ + n;
        float gi = bf2f(XP[xbase + 0 * H_]);
        float gf = bf2f(XP[xbase + 1 * H_]);
        float gg = bf2f(XP[xbase + 2 * H_]);
        float go = bf2f(XP[xbase + 3 * H_]);
        if (!skip) {
            gi += lds_g[0][br][nn];
            gf += lds_g[1][br][nn];
            gg += lds_g[2][br][nn];
            go += lds_g[3][br][nn];
        }
        float cprev;
        if (cell == 0) {
            int pi = father_idx[b * T_ + i];
            cprev = cS[((size_t)(b * T_ + pi)) * H_ + n];
        } else {
            cprev = reset ? 0.f : bcS[((size_t)(b * T_ + (i - 1))) * H_ + n];
        }
        float c2 = sigf(gf) * cprev + sigf(gi) * tanh_fast(gg);
        float h2 = sigf(go) * tanh_fast(c2);
        if (cell == 0) cS[((size_t)(b * T_ + i)) * H_ + n] = c2;
        else           bcS[((size_t)(b * T_ + i)) * H_ + n] = c2;
        H_all[(((size_t)(b * T_ + i)) * 2 + cell) * H_ + n] = f2bf(h2);
    }
}

// ---------------------------------------------------------------------------
// In-place row log-softmax over V=10000, one block per row.
__global__ __launch_bounds__(256) void softmax_k(float* __restrict__ out) {
    __shared__ float buf[V_];
    __shared__ float red[4];
    int r = blockIdx.x;
    float* row = out + (size_t)r * V_;
    int tid = threadIdx.x;
    float lmax = -1e30f;
    for (int t = tid; t < V_; t += 256) {
        float v = row[t];
        buf[t] = v;
        lmax = fmaxf(lmax, v);
    }
#pragma unroll
    for (int o = 32; o; o >>= 1) lmax = fmaxf(lmax, __shfl_xor(lmax, o));
    if ((tid & 63) == 0) red[tid >> 6] = lmax;
    __syncthreads();
    float gmax = fmaxf(fmaxf(red[0], red[1]), fmaxf(red[2], red[3]));
    float ls = 0.f;
    for (int t = tid; t < V_; t += 256) ls += __expf(buf[t] - gmax);
#pragma unroll
    for (int o = 32; o; o >>= 1) ls += __shfl_xor(ls, o);
    __syncthreads();
    if ((tid & 63) == 0) red[tid >> 6] = ls;
    __syncthreads();
    float lse = gmax + __logf(red[0] + red[1] + red[2] + red[3]);
    for (int t = tid; t < V_; t += 256) row[t] = buf[t] - lse;
}

// ---------------------------------------------------------------------------
extern "C" void kernel_launch(void* const* d_in, const int* in_sizes, int n_in,
                              void* d_out, int out_size, void* d_ws, size_t ws_size,
                              hipStream_t stream) {
    const int* word_idx = (const int*)d_in[0];
    const int* father_idx = (const int*)d_in[1];
    const float* fc_feats = (const float*)d_in[2];
    const float* embed = (const float*)d_in[3];
    const float* fc_w = (const float*)d_in[4];
    const float* fc_b = (const float*)d_in[5];
    const float* a_wih = (const float*)d_in[6];
    const float* a_whh = (const float*)d_in[7];
    const float* a_bih = (const float*)d_in[8];
    const float* a_bhh = (const float*)d_in[9];
    const float* f_wih = (const float*)d_in[10];
    const float* f_whh = (const float*)d_in[11];
    const float* f_bih = (const float*)d_in[12];
    const float* f_bhh = (const float*)d_in[13];
    const float* pred_w = (const float*)d_in[14];
    const float* pred_b = (const float*)d_in[15];
    const float* logit_w = (const float*)d_in[16];
    const float* logit_b = (const float*)d_in[17];
    float* out = (float*)d_out;

    char* ws = (char*)d_ws;
    size_t off = 0;
    auto alloc = [&](size_t bytes) {
        void* p = ws + off;
        off += (bytes + 255) & ~(size_t)255;
        return p;
    };
    short* a_wih_h   = (short*)alloc((size_t)G_ * E_ * 2);
    short* f_wih_h   = (short*)alloc((size_t)G_ * E_ * 2);
    short* a_whh_h   = (short*)alloc((size_t)G_ * H_ * 2);
    short* f_whh_h   = (short*)alloc((size_t)G_ * H_ * 2);
    short* fc_w_h    = (short*)alloc((size_t)E_ * F_ * 2);
    short* pred_w_h  = (short*)alloc((size_t)H_ * 2 * H_ * 2);
    short* logit_w_h = (short*)alloc((size_t)V_ * H_ * 2);
    short* fc_feats_h= (short*)alloc((size_t)B_ * F_ * 2);
    float* bias_a    = (float*)alloc((size_t)G_ * 4);
    float* bias_f    = (float*)alloc((size_t)G_ * 4);
    short* XaIn      = (short*)alloc((size_t)B_ * T_ * E_ * 2);
    short* XfIn      = (short*)alloc((size_t)B_ * T_ * E_ * 2);
    short* XaP       = (short*)alloc((size_t)B_ * T_ * G_ * 2);
    short* XfP       = (short*)alloc((size_t)B_ * T_ * G_ * 2);
    short* H_all     = (short*)alloc((size_t)B_ * T_ * 2 * H_ * 2);
    float* cS        = (float*)alloc((size_t)B_ * T_ * H_ * 4);
    float* bcS       = (float*)alloc((size_t)B_ * T_ * H_ * 4);
    short* OUTb      = (short*)alloc((size_t)B_ * T_ * H_ * 2);
    if (off > ws_size) return;  // ~109 MB needed; leaves output poisoned -> loud failure

    // Phase 0: dtype converts + combined biases
    convert_k<<<1024, 256, 0, stream>>>(a_wih, a_wih_h, G_ * E_);
    convert_k<<<1024, 256, 0, stream>>>(f_wih, f_wih_h, G_ * E_);
    convert_k<<<1024, 256, 0, stream>>>(a_whh, a_whh_h, G_ * H_);
    convert_k<<<1024, 256, 0, stream>>>(f_whh, f_whh_h, G_ * H_);
    convert_k<<<1024, 256, 0, stream>>>(fc_w, fc_w_h, E_ * F_);
    convert_k<<<1024, 256, 0, stream>>>(pred_w, pred_w_h, H_ * 2 * H_);
    convert_k<<<2048, 256, 0, stream>>>(logit_w, logit_w_h, V_ * H_);
    convert_k<<<1024, 256, 0, stream>>>(fc_feats, fc_feats_h, B_ * F_);
    bias2_k<<<16, 256, 0, stream>>>(a_bih, a_bhh, bias_a, f_bih, f_bhh, bias_f);

    // Phase 1: x_a0 = fc_feats @ fc_w.T + fc_b  -> bf16 rows (b, i=0) of XaIn
    gemm_bt<1, 0><<<dim3(4, 1), 256, 0, stream>>>(fc_feats_h, F_, fc_w_h, fc_b,
                                                  XaIn, T_ * E_, B_, E_, F_);
    // gather embeddings for all other rows
    gather_k<<<B_ * T_, 256, 0, stream>>>(word_idx, father_idx, embed, XaIn, XfIn);
    // batched input projections (bias folded in): XP = XIn @ wih.T + (bih+bhh)
    gemm_bt<1, 0><<<dim3(16, 40), 256, 0, stream>>>(XaIn, E_, a_wih_h, bias_a,
                                                    XaP, G_, B_ * T_, G_, E_);
    gemm_bt<1, 0><<<dim3(16, 40), 256, 0, stream>>>(XfIn, E_, f_wih_h, bias_f,
                                                    XfP, G_, B_ * T_, G_, E_);

    // Phase 2: recurrence
    step0_k<<<(B_ * H_) / 256, 256, 0, stream>>>(XaP, XfP, H_all, cS, bcS);
    for (int i = 1; i < T_; i++) {
        int reset = (((i - 1) % 3) == 0) ? 1 : 0;
        step_k<<<64, 256, 0, stream>>>(XaP, XfP, a_whh_h, f_whh_h, H_all, cS, bcS,
                                       father_idx, i, reset);
    }

    // Phase 3: pred head, logits, log-softmax
    gemm_bt<1, 1><<<dim3(4, 40), 256, 0, stream>>>(H_all, 2 * H_, pred_w_h, pred_b,
                                                   OUTb, H_, B_ * T_, H_, 2 * H_);
    gemm_bt<0, 0><<<dim3(79, 40), 256, 0, stream>>>(OUTb, H_, logit_w_h, logit_b,
                                                    out, V_, B_ * T_, V_, H_);
    softmax_k<<<B_ * T_, 256, 0, stream>>>(out);
}